// Round 10
// baseline (249.537 us; speedup 1.0000x reference)
//
#include <hip/hip_runtime.h>
#include <hip/hip_fp16.h>
#include <math.h>

#define N_NODES 50000
#define N_EDGES 800000
#define BIGV 1000000000.0f
#define NBLK_SCAN 196   // ceil(50000/256)
#define NBLK_GEMM 782   // ceil(50000/64); 64 nodes per block (16 per wave)

typedef _Float16 half8 __attribute__((ext_vector_type(8)));
typedef float floatx4 __attribute__((ext_vector_type(4)));

__device__ __forceinline__ float clampinf(float x) { return isinf(x) ? BIGV : x; }

// ---------------------------------------------------------------------------
// W pre-cast: wt[n][k] = (fp16) W[k][n]  (128x128, 32 KB) — run once, tiny.
// ---------------------------------------------------------------------------
__global__ __launch_bounds__(256) void k_wcast(const float* __restrict__ W,
                                               __half* __restrict__ wt)
{
    int idx = blockIdx.x * 256 + threadIdx.x;   // 0..16383
    int n = idx >> 7, k = idx & 127;
    wt[idx] = __float2half(W[k * 128 + n]);
}

// ---------------------------------------------------------------------------
// K1 (barrier-free): z = h @ W + b via MFMA f16, fp16 z out, fused scores
// s=z.w_src / t=z.w_dst, fused dst-histogram + rank (atomic return value).
// EACH WAVE owns 16 nodes end-to-end: stages its own h rows into a private
// LDS slice (no __syncthreads anywhere), computes all 128 cols (8 strips x
// 4 k-steps = 32 MFMAs), reduces sv/tv in-register via 16-lane shuffles.
// Fragment layouts (m89-verified):
//   A[m=lane&15][k=oct*8+j], B[k=oct*8+j][n=lane&15], C/D col=lane&15,
//   row=oct*4+reg  (oct = lane>>4).
// ---------------------------------------------------------------------------
__global__ __launch_bounds__(256) void k_gemm(
    const float* __restrict__ h, const __half* __restrict__ wt,
    const float* __restrict__ bias, const float* __restrict__ attn_w,
    const int* __restrict__ dst, __half* __restrict__ zh,
    float* __restrict__ sv, float* __restrict__ tv,
    int* __restrict__ cursor, int* __restrict__ rank)
{
    __shared__ _Float16 hA[4][16][136];   // per-wave private slice (~17.4 KB)

    const int tid = threadIdx.x;
    const int lane = tid & 63;
    const int wv = tid >> 6;          // wave 0..3
    const int l16 = lane & 15;
    const int oct = lane >> 4;

    // fused histogram + rank: grid-stride, issued FIRST so the atomics
    // retire under the GEMM (782*256 = 200192 stride, 4 iters).
    for (int e = blockIdx.x * 256 + tid; e < N_EDGES; e += NBLK_GEMM * 256)
        rank[e] = atomicAdd(&cursor[dst[e]], 1);

    const int node0 = blockIdx.x * 64 + wv * 16;
    if (node0 >= N_NODES) return;     // tail waves idle (no barriers -> safe)

    // stage this wave's 16 h rows as fp16 (512 float4, 8 per lane)
    _Float16 (*A)[136] = hA[wv];
    {
        const float4* h4 = (const float4*)(h + (size_t)node0 * 128);
        #pragma unroll
        for (int i = 0; i < 8; ++i) {
            int idx = lane + i * 64;
            int r = idx >> 5, c4 = idx & 31;
            float4 v = h4[idx];
            union { __half2 h2[2]; uint2 u; } pk;
            pk.h2[0] = __floats2half2_rn(v.x, v.y);
            pk.h2[1] = __floats2half2_rn(v.z, v.w);
            *(uint2*)&A[r][c4 << 2] = pk.u;
        }
    }
    // no __syncthreads: same-wave LDS dependency, compiler emits lgkmcnt

    floatx4 acc[8] = {{0,0,0,0},{0,0,0,0},{0,0,0,0},{0,0,0,0},
                      {0,0,0,0},{0,0,0,0},{0,0,0,0},{0,0,0,0}};
    #pragma unroll
    for (int kk = 0; kk < 4; ++kk) {
        half8 a = *(const half8*)&A[l16][(kk << 5) + (oct << 3)];
        #pragma unroll
        for (int s = 0; s < 8; ++s) {
            half8 b = *(const half8*)(wt + (size_t)(s * 16 + l16) * 128
                                         + (kk << 5) + (oct << 3));
            acc[s] = __builtin_amdgcn_mfma_f32_16x16x32_f16(a, b, acc[s], 0, 0, 0);
        }
    }

    // epilogue: bias + clamp + zh store + fused score partials
    float bv[8], ws[8], wd[8];
    #pragma unroll
    for (int s = 0; s < 8; ++s) {
        bv[s] = bias[s * 16 + l16];
        ws[s] = attn_w[s * 16 + l16];
        wd[s] = attn_w[128 + s * 16 + l16];
    }
    #pragma unroll
    for (int r = 0; r < 4; ++r) {
        const int row = (oct << 2) + r;
        float s_acc = 0.f, t_acc = 0.f;
        #pragma unroll
        for (int s = 0; s < 8; ++s) {
            float z = clampinf(acc[s][r] + bv[s]);
            zh[(size_t)(node0 + row) * 128 + s * 16 + l16] = __float2half(z);
            s_acc = fmaf(z, ws[s], s_acc);
            t_acc = fmaf(z, wd[s], t_acc);
        }
        // reduce over the 16 cols (l16) inside each oct group
        #pragma unroll
        for (int o = 1; o < 16; o <<= 1) {
            s_acc += __shfl_xor(s_acc, o);
            t_acc += __shfl_xor(t_acc, o);
        }
        if (l16 == 0) {
            sv[node0 + row] = s_acc;
            tv[node0 + row] = t_acc;
        }
    }
}

// ---------------------------------------------------------------------------
// hierarchical scan: per-block sums -> root scan -> block-local scan
// ---------------------------------------------------------------------------
__global__ __launch_bounds__(256) void k_scan_bsum(const int* __restrict__ cursor,
                                                   int* __restrict__ bsum)
{
    __shared__ int s[256];
    const int t = threadIdx.x;
    const int idx = blockIdx.x * 256 + t;
    s[t] = (idx < N_NODES) ? cursor[idx] : 0;
    __syncthreads();
    for (int off = 128; off; off >>= 1) {
        if (t < off) s[t] += s[t + off];
        __syncthreads();
    }
    if (t == 0) bsum[blockIdx.x] = s[0];
}

__global__ __launch_bounds__(256) void k_scan_root(const int* __restrict__ bsum,
                                                   int* __restrict__ broot,
                                                   int* __restrict__ colptr)
{
    __shared__ int s[256];
    const int t = threadIdx.x;
    int v = (t < NBLK_SCAN) ? bsum[t] : 0;
    s[t] = v;
    __syncthreads();
    for (int off = 1; off < 256; off <<= 1) {
        int u = (t >= off) ? s[t - off] : 0;
        __syncthreads();
        s[t] += u;
        __syncthreads();
    }
    if (t < NBLK_SCAN) broot[t] = s[t] - v;      // exclusive
    if (t == 255) colptr[N_NODES] = s[255];
}

__global__ __launch_bounds__(256) void k_scan_final(const int* __restrict__ cursor_in,
                                                    const int* __restrict__ broot,
                                                    int* __restrict__ colptr)
{
    __shared__ int s[256];
    const int t = threadIdx.x;
    const int idx = blockIdx.x * 256 + t;
    int v = (idx < N_NODES) ? cursor_in[idx] : 0;
    s[t] = v;
    __syncthreads();
    for (int off = 1; off < 256; off <<= 1) {
        int u = (t >= off) ? s[t - off] : 0;
        __syncthreads();
        s[t] += u;
        __syncthreads();
    }
    if (idx < N_NODES) colptr[idx] = broot[blockIdx.x] + s[t] - v;
}

// ---------------------------------------------------------------------------
// scatter edges into CSR order as ONE 16B record {src, sigma, e, pad}.
// ATOMIC-FREE: pos = colptr[dst] + rank (rank assigned in k_gemm's histogram).
// ---------------------------------------------------------------------------
__global__ void k_scatter(const int* __restrict__ src, const int* __restrict__ dst,
                          const float* __restrict__ sigma,
                          const int* __restrict__ rank, const int* __restrict__ colptr,
                          const float* __restrict__ sv, const float* __restrict__ tv,
                          const float* __restrict__ attn_b,
                          float4* __restrict__ recs)
{
    int e = blockIdx.x * 256 + threadIdx.x;
    if (e < N_EDGES) {
        int s = src[e];
        int d = dst[e];
        float a = sv[s] + tv[d] + attn_b[0];
        a = clampinf(a);
        float ev = a > 0.f ? a : 0.01f * a;      // leaky relu
        int pos = colptr[d] + rank[e];
        float4 rec;
        rec.x = __int_as_float(s);
        rec.y = sigma[e];
        rec.z = ev;
        rec.w = 0.f;
        recs[pos] = rec;
    }
}

// ---------------------------------------------------------------------------
// K6: per-node softmax + weighted aggregate. One 64-lane wave per node.
// All __shfl executed wave-uniformly (ds_bpermute from inactive lanes is UB).
// ---------------------------------------------------------------------------
__global__ __launch_bounds__(256) void k_agg(
    const int* __restrict__ colptr, const float4* __restrict__ recs,
    const __half* __restrict__ zh, float* __restrict__ out)
{
    const int lane = threadIdx.x & 63;
    const int node = blockIdx.x * 4 + (threadIdx.x >> 6);
    if (node >= N_NODES) return;
    const int base = colptr[node];
    const int deg = colptr[node + 1] - base;

    const int grp = lane >> 4;   // 0..3: which edge of the 4 in flight
    const int l16 = lane & 15;   // feature octet within the row
    float acc[8] = {0.f, 0.f, 0.f, 0.f, 0.f, 0.f, 0.f, 0.f};

    if (deg > 0) {
        if (deg <= 64) {
            // ---- fast path: everything in registers ----
            int sidx = 0; float sig = 0.f, e = -INFINITY;
            if (lane < deg) {
                float4 r = recs[base + lane];
                sidx = __float_as_int(r.x); sig = r.y; e = r.z;
            }
            float m = e;
            for (int o = 32; o; o >>= 1) m = fmaxf(m, __shfl_xor(m, o));
            float p = (lane < deg) ? __expf(e - m) : 0.f;
            float dn = p, bs = sig;
            for (int o = 32; o; o >>= 1) {
                dn += __shfl_xor(dn, o);
                bs += __shfl_xor(bs, o);
            }
            const float coef = p * sig * (1.0f / dn) / (bs + 1e-6f);
            for (int c = 0; c < deg; c += 4) {
                const int j = c + grp;                 // j <= 63 always
                const int js = (j < deg) ? j : 0;      // clamp source index
                float cf = __shfl(coef, js);           // uniform: all lanes
                int sj = __shfl(sidx, js);
                if (j < deg) {
                    uint4 raw = *(const uint4*)(zh + ((size_t)sj << 7) + (l16 << 3));
                    const __half2* hp = (const __half2*)&raw;
                    #pragma unroll
                    for (int k = 0; k < 4; ++k) {
                        float2 f = __half22float2(hp[k]);
                        acc[2*k]   = fmaf(cf, f.x, acc[2*k]);
                        acc[2*k+1] = fmaf(cf, f.y, acc[2*k+1]);
                    }
                }
            }
        } else {
            // ---- generic path (deg > 64, rare) ----
            float m = -INFINITY;
            for (int i = lane; i < deg; i += 64) m = fmaxf(m, recs[base + i].z);
            for (int o = 32; o; o >>= 1) m = fmaxf(m, __shfl_xor(m, o));
            float dn = 0.f, bs = 0.f;
            for (int i = lane; i < deg; i += 64) {
                float4 r = recs[base + i];
                dn += __expf(r.z - m); bs += r.y;
            }
            for (int o = 32; o; o >>= 1) {
                dn += __shfl_xor(dn, o);
                bs += __shfl_xor(bs, o);
            }
            const float scale = (1.0f / dn) / (bs + 1e-6f);
            for (int c = 0; c < deg; c += 64) {
                int i = c + lane;
                int sidx = 0; float coef = 0.f;
                if (i < deg) {
                    float4 r = recs[base + i];
                    sidx = __float_as_int(r.x);
                    coef = __expf(r.z - m) * r.y * scale;
                }
                const int cnt = min(64, deg - c);
                for (int j = 0; j < cnt; j += 4) {
                    const int jj = j + grp;            // jj <= 63 always
                    const int js = (jj < cnt) ? jj : 0;
                    float cf = __shfl(coef, js);       // uniform: all lanes
                    int sj = __shfl(sidx, js);
                    if (jj < cnt) {
                        uint4 raw = *(const uint4*)(zh + ((size_t)sj << 7) + (l16 << 3));
                        const __half2* hp = (const __half2*)&raw;
                        #pragma unroll
                        for (int k = 0; k < 4; ++k) {
                            float2 f = __half22float2(hp[k]);
                            acc[2*k]   = fmaf(cf, f.x, acc[2*k]);
                            acc[2*k+1] = fmaf(cf, f.y, acc[2*k+1]);
                        }
                    }
                }
            }
        }
    }
    // combine the 4 groups: feature 8*l16+k lives in lanes {l16, l16+16, l16+32, l16+48}
    #pragma unroll
    for (int k = 0; k < 8; ++k) {
        acc[k] += __shfl_xor(acc[k], 16);
        acc[k] += __shfl_xor(acc[k], 32);
    }
    if (grp == 0) {
        float4 o0, o1;
        o0.x = clampinf(acc[0]); o0.y = clampinf(acc[1]);
        o0.z = clampinf(acc[2]); o0.w = clampinf(acc[3]);
        o1.x = clampinf(acc[4]); o1.y = clampinf(acc[5]);
        o1.z = clampinf(acc[6]); o1.w = clampinf(acc[7]);
        float4* op = (float4*)(out + (size_t)node * 128 + (l16 << 3));
        op[0] = o0; op[1] = o1;
    }
}

// ---------------------------------------------------------------------------
// BatchNorm: per-feature sum / sumsq partials + atomics, then fused apply+ELU
// ---------------------------------------------------------------------------
__global__ __launch_bounds__(256) void k_bnstats(const float* __restrict__ hnew,
                                                 float* __restrict__ sums)
{
    const int f = threadIdx.x & 127;
    const int half_ = threadIdx.x >> 7;
    float s = 0.f, q = 0.f;
    for (int node = blockIdx.x * 2 + half_; node < N_NODES; node += gridDim.x * 2) {
        float v = hnew[(size_t)node * 128 + f];
        s += v;
        q += v * v;
    }
    __shared__ float ls[256], lq[256];
    ls[threadIdx.x] = s; lq[threadIdx.x] = q;
    __syncthreads();
    if (half_ == 0) {
        s += ls[threadIdx.x + 128];
        q += lq[threadIdx.x + 128];
        atomicAdd(&sums[f], s);
        atomicAdd(&sums[128 + f], q);
    }
}

__global__ __launch_bounds__(256) void k_bnapply(float* __restrict__ io,
                                                 const float* __restrict__ sums,
                                                 const float* __restrict__ gamma,
                                                 const float* __restrict__ beta)
{
    const size_t idx = (size_t)blockIdx.x * 256 + threadIdx.x;
    const int f = (int)(idx & 127);
    const float invn = 1.0f / (float)N_NODES;
    float mu = sums[f] * invn;
    float var = fmaxf(sums[128 + f] * invn - mu * mu, 0.f);
    float rs = rsqrtf(var + 1e-5f);
    float x = io[idx];
    float y = (x - mu) * rs * gamma[f] + beta[f];
    io[idx] = y > 0.f ? y : expm1f(y);
}

// ---------------------------------------------------------------------------
extern "C" void kernel_launch(void* const* d_in, const int* in_sizes, int n_in,
                              void* d_out, int out_size, void* d_ws, size_t ws_size,
                              hipStream_t stream)
{
    const float* h      = (const float*)d_in[0];
    const int*   src    = (const int*)  d_in[1];
    const int*   dst    = (const int*)  d_in[2];
    const float* sigma  = (const float*)d_in[3];
    const float* fc_w   = (const float*)d_in[4];
    const float* fc_b   = (const float*)d_in[5];
    const float* attn_w = (const float*)d_in[6];
    const float* attn_b = (const float*)d_in[7];
    const float* gamma  = (const float*)d_in[8];
    const float* beta   = (const float*)d_in[9];
    float* out = (float*)d_out;

    // workspace layout (~30 MB)
    float4* recs   = (float4*)d_ws;                         // 800000 x 16B
    __half* zh     = (__half*)(recs + N_EDGES);             // 50000*128 fp16
    float*  sv     = (float*)(zh + (size_t)N_NODES * 128);  // 50000
    float*  tv     = sv + N_NODES;                          // 50000
    float*  bns    = tv + N_NODES;                          // 256
    int*    colptr = (int*)(bns + 256);                     // 50001 (pad 50004)
    int*    cursor = colptr + 50004;                        // 50000
    int*    bsum   = cursor + N_NODES;                      // 196 (pad 256)
    int*    broot  = bsum + 256;                            // 196 (pad 256)
    __half* wt     = (__half*)(broot + 256);                // 128*128 fp16 (W^T)
    int*    rank   = (int*)(wt + 128 * 128);                // 800000

    hipMemsetAsync(cursor, 0, N_NODES * sizeof(int), stream);
    hipMemsetAsync(bns, 0, 256 * sizeof(float), stream);

    k_wcast     <<<64, 256, 0, stream>>>(fc_w, wt);
    k_gemm      <<<NBLK_GEMM, 256, 0, stream>>>(h, wt, fc_b, attn_w, dst,
                                                zh, sv, tv, cursor, rank);
    k_scan_bsum <<<NBLK_SCAN, 256, 0, stream>>>(cursor, bsum);
    k_scan_root <<<1, 256, 0, stream>>>(bsum, broot, colptr);
    k_scan_final<<<NBLK_SCAN, 256, 0, stream>>>(cursor, broot, colptr);
    k_scatter   <<<N_EDGES / 256, 256, 0, stream>>>(src, dst, sigma, rank, colptr,
                                                    sv, tv, attn_b, recs);
    k_agg       <<<N_NODES / 4, 256, 0, stream>>>(colptr, recs, zh, out);
    k_bnstats   <<<256, 256, 0, stream>>>(out, bns);
    k_bnapply   <<<(N_NODES * 128) / 256, 256, 0, stream>>>(out, bns, gamma, beta);
}

// Round 11
// 230.751 us; speedup vs baseline: 1.0814x; 1.0814x over previous
//
#include <hip/hip_runtime.h>
#include <hip/hip_fp16.h>
#include <math.h>

#define N_NODES 50000
#define N_EDGES 800000
#define BIGV 1000000000.0f
#define NBLK_SCAN 196   // ceil(50000/256)
#define NBLK_GEMM 3125  // 50000 / 16 nodes per block

typedef _Float16 half8 __attribute__((ext_vector_type(8)));
typedef float floatx4 __attribute__((ext_vector_type(4)));

__device__ __forceinline__ float clampinf(float x) { return isinf(x) ? BIGV : x; }

// ---------------------------------------------------------------------------
// W pre-cast + workspace zeroing (fused to drop 2 memset dispatches).
// wt[n][k] = (fp16) W[k][n]  (128x128, 32 KB). 64 blocks x 256.
// ---------------------------------------------------------------------------
__global__ __launch_bounds__(256) void k_wcast(const float* __restrict__ W,
                                               __half* __restrict__ wt,
                                               int* __restrict__ cursor,
                                               float* __restrict__ bns)
{
    int idx = blockIdx.x * 256 + threadIdx.x;   // 0..16383
    int n = idx >> 7, k = idx & 127;
    wt[idx] = __float2half(W[k * 128 + n]);
    // zero cursor[50000]
    for (int i = idx; i < N_NODES; i += 16384) cursor[i] = 0;
    // zero bns[256]
    if (idx < 256) bns[idx] = 0.f;
}

// ---------------------------------------------------------------------------
// K1 (R9-proven): z = h @ W + b via MFMA f16 (fp32 accum), fp16 z out, fused
// per-node scores s=z.w_src / t=z.w_dst, fused dst-histogram + rank (atomic
// return value) — makes k_scatter atomic-free.
// Grid 3125 x 256 (16 nodes/block) for latency-hiding occupancy; each wave
// owns a 32-col strip with B-fragments in registers (L2-resident wt).
// Fragment layouts (m89-verified):
//   A[m=lane&15][k=oct*8+j], B[k=oct*8+j][n=lane&15], C/D col=lane&15,
//   row=oct*4+reg  (oct = lane>>4).
// ---------------------------------------------------------------------------
__global__ __launch_bounds__(256) void k_gemm(
    const float* __restrict__ h, const __half* __restrict__ wt,
    const float* __restrict__ bias, const float* __restrict__ attn_w,
    const int* __restrict__ dst, __half* __restrict__ zh,
    float* __restrict__ sv, float* __restrict__ tv,
    int* __restrict__ cursor, int* __restrict__ rank)
{
    __shared__ _Float16 hA[16][136];
    __shared__ float spart[4][16], tpart[4][16];

    const int tid = threadIdx.x;
    const int lane = tid & 63;
    const int wv = tid >> 6;          // wave 0..3
    const int l16 = lane & 15;
    const int oct = lane >> 4;
    const int n0 = wv << 5;           // this wave's 32-col strip
    const int node0 = blockIdx.x << 4;

    // fused histogram + rank: 1 coalesced edge/thread (3125*256 == 800000).
    const int e = blockIdx.x * 256 + tid;
    const int d = dst[e];
    // stage h tile as fp16 (512 float4; 32 float4 per row) — issued early
    {
        const float4* h4 = (const float4*)(h + (size_t)node0 * 128);
        for (int i = tid; i < 512; i += 256) {
            int r = i >> 5, c4 = i & 31;
            float4 v = h4[i];
            union { __half2 h2[2]; uint2 u; } pk;
            pk.h2[0] = __floats2half2_rn(v.x, v.y);
            pk.h2[1] = __floats2half2_rn(v.z, v.w);
            *(uint2*)&hA[r][c4 << 2] = pk.u;
        }
    }
    rank[e] = atomicAdd(&cursor[d], 1);

    // B-fragments in registers: bfrag[kk][t] covers k=[32kk,32kk+32), n=[n0+16t,+16)
    half8 bfrag[4][2];
    #pragma unroll
    for (int kk = 0; kk < 4; ++kk)
        #pragma unroll
        for (int t = 0; t < 2; ++t)
            bfrag[kk][t] = *(const half8*)(wt + (size_t)(n0 + t * 16 + l16) * 128
                                              + kk * 32 + oct * 8);

    const float bv0 = bias[n0 + l16],         bv1 = bias[n0 + 16 + l16];
    const float ws0 = attn_w[n0 + l16],       ws1 = attn_w[n0 + 16 + l16];
    const float wd0 = attn_w[128 + n0 + l16], wd1 = attn_w[128 + n0 + 16 + l16];

    __syncthreads();

    floatx4 acc0 = {0.f, 0.f, 0.f, 0.f};
    floatx4 acc1 = {0.f, 0.f, 0.f, 0.f};
    #pragma unroll
    for (int kk = 0; kk < 4; ++kk) {
        half8 a = *(const half8*)&hA[l16][(kk << 5) + (oct << 3)];
        acc0 = __builtin_amdgcn_mfma_f32_16x16x32_f16(a, bfrag[kk][0], acc0, 0, 0, 0);
        acc1 = __builtin_amdgcn_mfma_f32_16x16x32_f16(a, bfrag[kk][1], acc1, 0, 0, 0);
    }

    float s_acc[4], t_acc[4];
    #pragma unroll
    for (int r = 0; r < 4; ++r) {
        float z0 = clampinf(acc0[r] + bv0);
        float z1 = clampinf(acc1[r] + bv1);
        const int row = (oct << 2) + r;
        zh[(size_t)(node0 + row) * 128 + n0 + l16]      = __float2half(z0);
        zh[(size_t)(node0 + row) * 128 + n0 + 16 + l16] = __float2half(z1);
        s_acc[r] = z0 * ws0 + z1 * ws1;
        t_acc[r] = z0 * wd0 + z1 * wd1;
    }
    #pragma unroll
    for (int r = 0; r < 4; ++r) {
        #pragma unroll
        for (int o = 1; o < 16; o <<= 1) {
            s_acc[r] += __shfl_xor(s_acc[r], o);
            t_acc[r] += __shfl_xor(t_acc[r], o);
        }
    }
    if (l16 == 0) {
        #pragma unroll
        for (int r = 0; r < 4; ++r) {
            spart[wv][(oct << 2) + r] = s_acc[r];
            tpart[wv][(oct << 2) + r] = t_acc[r];
        }
    }
    __syncthreads();
    if (tid < 16) {
        sv[node0 + tid] = spart[0][tid] + spart[1][tid] + spart[2][tid] + spart[3][tid];
        tv[node0 + tid] = tpart[0][tid] + tpart[1][tid] + tpart[2][tid] + tpart[3][tid];
    }
}

// ---------------------------------------------------------------------------
// scan phase 1: per-block sums of cursor
// ---------------------------------------------------------------------------
__global__ __launch_bounds__(256) void k_scan_bsum(const int* __restrict__ cursor,
                                                   int* __restrict__ bsum)
{
    __shared__ int s[256];
    const int t = threadIdx.x;
    const int idx = blockIdx.x * 256 + t;
    s[t] = (idx < N_NODES) ? cursor[idx] : 0;
    __syncthreads();
    for (int off = 128; off; off >>= 1) {
        if (t < off) s[t] += s[t + off];
        __syncthreads();
    }
    if (t == 0) bsum[blockIdx.x] = s[0];
}

// ---------------------------------------------------------------------------
// scan phase 2 (merged root+final): every block redundantly scans the 196
// block-sums in LDS (800 B — trivial), takes its own exclusive offset, then
// does its block-local scan of cursor and writes colptr.
// ---------------------------------------------------------------------------
__global__ __launch_bounds__(256) void k_scan_final(const int* __restrict__ bsum,
                                                    const int* __restrict__ cursor_in,
                                                    int* __restrict__ colptr)
{
    __shared__ int rs[256];
    __shared__ int s[256];
    const int t = threadIdx.x;

    // root scan (all blocks do the same tiny scan)
    int rv = (t < NBLK_SCAN) ? bsum[t] : 0;
    rs[t] = rv;
    __syncthreads();
    for (int off = 1; off < 256; off <<= 1) {
        int u = (t >= off) ? rs[t - off] : 0;
        __syncthreads();
        rs[t] += u;
        __syncthreads();
    }
    const int broot = (blockIdx.x > 0) ? rs[blockIdx.x - 1] : 0;   // exclusive
    if (blockIdx.x == 0 && t == 255) colptr[N_NODES] = rs[255];

    // block-local scan
    const int idx = blockIdx.x * 256 + t;
    int v = (idx < N_NODES) ? cursor_in[idx] : 0;
    s[t] = v;
    __syncthreads();
    for (int off = 1; off < 256; off <<= 1) {
        int u = (t >= off) ? s[t - off] : 0;
        __syncthreads();
        s[t] += u;
        __syncthreads();
    }
    if (idx < N_NODES) colptr[idx] = broot + s[t] - v;
}

// ---------------------------------------------------------------------------
// scatter edges into CSR order as ONE 16B record {src, sigma, e, pad}.
// ATOMIC-FREE: pos = colptr[dst] + rank (rank assigned in k_gemm's histogram).
// ---------------------------------------------------------------------------
__global__ void k_scatter(const int* __restrict__ src, const int* __restrict__ dst,
                          const float* __restrict__ sigma,
                          const int* __restrict__ rank, const int* __restrict__ colptr,
                          const float* __restrict__ sv, const float* __restrict__ tv,
                          const float* __restrict__ attn_b,
                          float4* __restrict__ recs)
{
    int e = blockIdx.x * 256 + threadIdx.x;
    if (e < N_EDGES) {
        int s = src[e];
        int d = dst[e];
        float a = sv[s] + tv[d] + attn_b[0];
        a = clampinf(a);
        float ev = a > 0.f ? a : 0.01f * a;      // leaky relu
        int pos = colptr[d] + rank[e];
        float4 rec;
        rec.x = __int_as_float(s);
        rec.y = sigma[e];
        rec.z = ev;
        rec.w = 0.f;
        recs[pos] = rec;
    }
}

// ---------------------------------------------------------------------------
// K6: per-node softmax + weighted aggregate. One 64-lane wave per node.
// All __shfl executed wave-uniformly (ds_bpermute from inactive lanes is UB).
// ---------------------------------------------------------------------------
__global__ __launch_bounds__(256) void k_agg(
    const int* __restrict__ colptr, const float4* __restrict__ recs,
    const __half* __restrict__ zh, float* __restrict__ out)
{
    const int lane = threadIdx.x & 63;
    const int node = blockIdx.x * 4 + (threadIdx.x >> 6);
    if (node >= N_NODES) return;
    const int base = colptr[node];
    const int deg = colptr[node + 1] - base;

    const int grp = lane >> 4;   // 0..3: which edge of the 4 in flight
    const int l16 = lane & 15;   // feature octet within the row
    float acc[8] = {0.f, 0.f, 0.f, 0.f, 0.f, 0.f, 0.f, 0.f};

    if (deg > 0) {
        if (deg <= 64) {
            // ---- fast path: everything in registers ----
            int sidx = 0; float sig = 0.f, e = -INFINITY;
            if (lane < deg) {
                float4 r = recs[base + lane];
                sidx = __float_as_int(r.x); sig = r.y; e = r.z;
            }
            float m = e;
            for (int o = 32; o; o >>= 1) m = fmaxf(m, __shfl_xor(m, o));
            float p = (lane < deg) ? __expf(e - m) : 0.f;
            float dn = p, bs = sig;
            for (int o = 32; o; o >>= 1) {
                dn += __shfl_xor(dn, o);
                bs += __shfl_xor(bs, o);
            }
            const float coef = p * sig * (1.0f / dn) / (bs + 1e-6f);
            for (int c = 0; c < deg; c += 4) {
                const int j = c + grp;                 // j <= 63 always
                const int js = (j < deg) ? j : 0;      // clamp source index
                float cf = __shfl(coef, js);           // uniform: all lanes
                int sj = __shfl(sidx, js);
                if (j < deg) {
                    uint4 raw = *(const uint4*)(zh + ((size_t)sj << 7) + (l16 << 3));
                    const __half2* hp = (const __half2*)&raw;
                    #pragma unroll
                    for (int k = 0; k < 4; ++k) {
                        float2 f = __half22float2(hp[k]);
                        acc[2*k]   = fmaf(cf, f.x, acc[2*k]);
                        acc[2*k+1] = fmaf(cf, f.y, acc[2*k+1]);
                    }
                }
            }
        } else {
            // ---- generic path (deg > 64, rare) ----
            float m = -INFINITY;
            for (int i = lane; i < deg; i += 64) m = fmaxf(m, recs[base + i].z);
            for (int o = 32; o; o >>= 1) m = fmaxf(m, __shfl_xor(m, o));
            float dn = 0.f, bs = 0.f;
            for (int i = lane; i < deg; i += 64) {
                float4 r = recs[base + i];
                dn += __expf(r.z - m); bs += r.y;
            }
            for (int o = 32; o; o >>= 1) {
                dn += __shfl_xor(dn, o);
                bs += __shfl_xor(bs, o);
            }
            const float scale = (1.0f / dn) / (bs + 1e-6f);
            for (int c = 0; c < deg; c += 64) {
                int i = c + lane;
                int sidx = 0; float coef = 0.f;
                if (i < deg) {
                    float4 r = recs[base + i];
                    sidx = __float_as_int(r.x);
                    coef = __expf(r.z - m) * r.y * scale;
                }
                const int cnt = min(64, deg - c);
                for (int j = 0; j < cnt; j += 4) {
                    const int jj = j + grp;            // jj <= 63 always
                    const int js = (jj < cnt) ? jj : 0;
                    float cf = __shfl(coef, js);       // uniform: all lanes
                    int sj = __shfl(sidx, js);
                    if (jj < cnt) {
                        uint4 raw = *(const uint4*)(zh + ((size_t)sj << 7) + (l16 << 3));
                        const __half2* hp = (const __half2*)&raw;
                        #pragma unroll
                        for (int k = 0; k < 4; ++k) {
                            float2 f = __half22float2(hp[k]);
                            acc[2*k]   = fmaf(cf, f.x, acc[2*k]);
                            acc[2*k+1] = fmaf(cf, f.y, acc[2*k+1]);
                        }
                    }
                }
            }
        }
    }
    // combine the 4 groups: feature 8*l16+k lives in lanes {l16, l16+16, l16+32, l16+48}
    #pragma unroll
    for (int k = 0; k < 8; ++k) {
        acc[k] += __shfl_xor(acc[k], 16);
        acc[k] += __shfl_xor(acc[k], 32);
    }
    if (grp == 0) {
        float4 o0, o1;
        o0.x = clampinf(acc[0]); o0.y = clampinf(acc[1]);
        o0.z = clampinf(acc[2]); o0.w = clampinf(acc[3]);
        o1.x = clampinf(acc[4]); o1.y = clampinf(acc[5]);
        o1.z = clampinf(acc[6]); o1.w = clampinf(acc[7]);
        float4* op = (float4*)(out + (size_t)node * 128 + (l16 << 3));
        op[0] = o0; op[1] = o1;
    }
}

// ---------------------------------------------------------------------------
// BatchNorm: per-feature sum / sumsq partials + atomics, then fused apply+ELU
// ---------------------------------------------------------------------------
__global__ __launch_bounds__(256) void k_bnstats(const float* __restrict__ hnew,
                                                 float* __restrict__ sums)
{
    const int f = threadIdx.x & 127;
    const int half_ = threadIdx.x >> 7;
    float s = 0.f, q = 0.f;
    for (int node = blockIdx.x * 2 + half_; node < N_NODES; node += gridDim.x * 2) {
        float v = hnew[(size_t)node * 128 + f];
        s += v;
        q += v * v;
    }
    __shared__ float ls[256], lq[256];
    ls[threadIdx.x] = s; lq[threadIdx.x] = q;
    __syncthreads();
    if (half_ == 0) {
        s += ls[threadIdx.x + 128];
        q += lq[threadIdx.x + 128];
        atomicAdd(&sums[f], s);
        atomicAdd(&sums[128 + f], q);
    }
}

__global__ __launch_bounds__(256) void k_bnapply(float* __restrict__ io,
                                                 const float* __restrict__ sums,
                                                 const float* __restrict__ gamma,
                                                 const float* __restrict__ beta)
{
    const size_t idx = (size_t)blockIdx.x * 256 + threadIdx.x;
    const int f = (int)(idx & 127);
    const float invn = 1.0f / (float)N_NODES;
    float mu = sums[f] * invn;
    float var = fmaxf(sums[128 + f] * invn - mu * mu, 0.f);
    float rs = rsqrtf(var + 1e-5f);
    float x = io[idx];
    float y = (x - mu) * rs * gamma[f] + beta[f];
    io[idx] = y > 0.f ? y : expm1f(y);
}

// ---------------------------------------------------------------------------
extern "C" void kernel_launch(void* const* d_in, const int* in_sizes, int n_in,
                              void* d_out, int out_size, void* d_ws, size_t ws_size,
                              hipStream_t stream)
{
    const float* h      = (const float*)d_in[0];
    const int*   src    = (const int*)  d_in[1];
    const int*   dst    = (const int*)  d_in[2];
    const float* sigma  = (const float*)d_in[3];
    const float* fc_w   = (const float*)d_in[4];
    const float* fc_b   = (const float*)d_in[5];
    const float* attn_w = (const float*)d_in[6];
    const float* attn_b = (const float*)d_in[7];
    const float* gamma  = (const float*)d_in[8];
    const float* beta   = (const float*)d_in[9];
    float* out = (float*)d_out;

    // workspace layout (~30 MB)
    float4* recs   = (float4*)d_ws;                         // 800000 x 16B
    __half* zh     = (__half*)(recs + N_EDGES);             // 50000*128 fp16
    float*  sv     = (float*)(zh + (size_t)N_NODES * 128);  // 50000
    float*  tv     = sv + N_NODES;                          // 50000
    float*  bns    = tv + N_NODES;                          // 256
    int*    colptr = (int*)(bns + 256);                     // 50001 (pad 50004)
    int*    cursor = colptr + 50004;                        // 50000
    int*    bsum   = cursor + N_NODES;                      // 196 (pad 256)
    int*    broot  = bsum + 256;                            // 196 (pad 256, unused now)
    __half* wt     = (__half*)(broot + 256);                // 128*128 fp16 (W^T)
    int*    rank   = (int*)(wt + 128 * 128);                // 800000

    k_wcast     <<<64, 256, 0, stream>>>(fc_w, wt, cursor, bns);
    k_gemm      <<<NBLK_GEMM, 256, 0, stream>>>(h, wt, fc_b, attn_w, dst,
                                                zh, sv, tv, cursor, rank);
    k_scan_bsum <<<NBLK_SCAN, 256, 0, stream>>>(cursor, bsum);
    k_scan_final<<<NBLK_SCAN, 256, 0, stream>>>(bsum, cursor, colptr);
    k_scatter   <<<N_EDGES / 256, 256, 0, stream>>>(src, dst, sigma, rank, colptr,
                                                    sv, tv, attn_b, recs);
    k_agg       <<<N_NODES / 4, 256, 0, stream>>>(colptr, recs, zh, out);
    k_bnstats   <<<256, 256, 0, stream>>>(out, bns);
    k_bnapply   <<<(N_NODES * 128) / 256, 256, 0, stream>>>(out, bns, gamma, beta);
}